// Round 19
// baseline (139.624 us; speedup 1.0000x reference)
//
#include <hip/hip_runtime.h>
#include <math.h>

// ---- problem constants ----
#define NE   1024
#define ROWS 16384
#define BM   64
#define SQ8F 2.8284271247461903f   // float32(math.sqrt(8)) as numpy casts it

// ---- workspace layout (bytes); Apart LAST so its size can flex with ws_size ----
#define WP_OFF   0u          // Wp: [2r][8oct][1024k][8c] f32 = 524288
#define BQK_OFF  524288u     // bqk: 128 f32 = 512
#define QP_OFF   524800u     // qPg: 16384*16 f32 = 1048576
#define KP_OFF   1573376u    // kPg: 16384*16 f32 = 1048576   [t][16]
#define KPT_OFF  2621952u    // kPgT: [64 chain][4096 t] f32 = 1048576
#define SP2_OFF  3670528u    // Spart2: 4*64*16*64 f32 = 1048576
#define KS_OFF   4719104u    // kSumF: 64 f32 = 256
#define QG_OFF   4719360u    // qg: 16384*64 f32 = 4194304
#define KG_OFF   8913664u    // kg: 16384*64 f32 = 4194304
#define AP_OFF   13107968u   // Apart: 4*Ts tiles * 16*1024 f32 (Ts=64 -> 16 MB)

// ---------------- K0: pack Wp k-major per 8-col octet (pure copy), bqk = [bq | bk]
__global__ __launch_bounds__(256) void k0_pack(
    const float* __restrict__ Wq, const float* __restrict__ bq,
    const float* __restrict__ Wk, const float* __restrict__ bk,
    float* __restrict__ Wp, float* __restrict__ bqk)
{
    int idx = blockIdx.x * 256 + threadIdx.x;
    if (idx < 32768) {                       // 2 roles * 1024 k * 16 float4
        int role = idx >> 14;
        int rem  = idx & 16383;
        int k = rem >> 4, c4 = rem & 15;
        float4 v = ((const float4*)(role ? Wk : Wq))[k * 16 + c4];
        int oct = c4 >> 1, pos = c4 & 1;
        ((float4*)Wp)[(size_t)(role * 8 + oct) * 2048 + k * 2 + pos] = v;
    } else if (idx < 32768 + 128) {
        int j = idx - 32768;
        bqk[j] = (j < 64) ? bq[j] : bk[j - 64];
    }
}

// ---------------- K1: 1024 blocks x 256 thr: GEMM only, C=8 cols/thread.
// Round-14 structure + software-pipelined W s_loads: per kq, drain current W
// (anchor = xa.x FMAs), THEN issue next kq's s_loads (sched_barrier pins them
// below the drain), then remaining FMAs — next drain finds loads ~70+ cyc old.
// FMA value-order identical to round 14 (bit-exact).
__global__ __launch_bounds__(256, 4) void k1_main(
    const float* __restrict__ x, const float* __restrict__ Wp,
    const float* __restrict__ bqk,
    float* __restrict__ qg, float* __restrict__ kg)
{
    __shared__ float xs[2][64][36];   // x chunk (K=32), double-buffered, 18 KB

    const int t    = threadIdx.x;
    const int lane = t & 63;
    const int wv   = __builtin_amdgcn_readfirstlane(t >> 6);   // 0..3
    const int bid  = blockIdx.x;
    const int variant = bid >> 8;     // 0..3: 32-col slice
    const int rb      = bid & 255;
    const int role = variant >> 1;
    const int octg = (variant & 1) * 4 + wv;   // 0..7 octet within role
    const int row0 = rb * 64;

    float acc[8];
    #pragma unroll
    for (int j = 0; j < 8; ++j) acc[j] = 0.f;

    const int srow = t >> 2;          // 0..63
    const int sc   = t & 3;           // 0..3 (8 floats each)
    const float* gsrc = x + (size_t)(row0 + srow) * NE + sc * 8;

    const float* wbase = Wp + (size_t)(role * 8 + octg) * 8192;  // wave-uniform

    float4 pf0 = *(const float4*)gsrc;
    float4 pf1 = *(const float4*)(gsrc + 4);
    *(float4*)&xs[0][srow][sc * 8]     = pf0;
    *(float4*)&xs[0][srow][sc * 8 + 4] = pf1;
    __syncthreads();

#define WK_ANCHOR(XA, CUR)                         \
    { float4 wa = CUR[0], wb = CUR[1];             \
      acc[0] = fmaf(XA.x, wa.x, acc[0]);           \
      acc[1] = fmaf(XA.x, wa.y, acc[1]);           \
      acc[2] = fmaf(XA.x, wa.z, acc[2]);           \
      acc[3] = fmaf(XA.x, wa.w, acc[3]);           \
      acc[4] = fmaf(XA.x, wb.x, acc[4]);           \
      acc[5] = fmaf(XA.x, wb.y, acc[5]);           \
      acc[6] = fmaf(XA.x, wb.z, acc[6]);           \
      acc[7] = fmaf(XA.x, wb.w, acc[7]); }

#define WK_REST(XA, CUR)                           \
    { float4 wa = CUR[2], wb = CUR[3];             \
      acc[0] = fmaf(XA.y, wa.x, acc[0]);           \
      acc[1] = fmaf(XA.y, wa.y, acc[1]);           \
      acc[2] = fmaf(XA.y, wa.z, acc[2]);           \
      acc[3] = fmaf(XA.y, wa.w, acc[3]);           \
      acc[4] = fmaf(XA.y, wb.x, acc[4]);           \
      acc[5] = fmaf(XA.y, wb.y, acc[5]);           \
      acc[6] = fmaf(XA.y, wb.z, acc[6]);           \
      acc[7] = fmaf(XA.y, wb.w, acc[7]);           \
      wa = CUR[4]; wb = CUR[5];                    \
      acc[0] = fmaf(XA.z, wa.x, acc[0]);           \
      acc[1] = fmaf(XA.z, wa.y, acc[1]);           \
      acc[2] = fmaf(XA.z, wa.z, acc[2]);           \
      acc[3] = fmaf(XA.z, wa.w, acc[3]);           \
      acc[4] = fmaf(XA.z, wb.x, acc[4]);           \
      acc[5] = fmaf(XA.z, wb.y, acc[5]);           \
      acc[6] = fmaf(XA.z, wb.z, acc[6]);           \
      acc[7] = fmaf(XA.z, wb.w, acc[7]);           \
      wa = CUR[6]; wb = CUR[7];                    \
      acc[0] = fmaf(XA.w, wa.x, acc[0]);           \
      acc[1] = fmaf(XA.w, wa.y, acc[1]);           \
      acc[2] = fmaf(XA.w, wa.z, acc[2]);           \
      acc[3] = fmaf(XA.w, wa.w, acc[3]);           \
      acc[4] = fmaf(XA.w, wb.x, acc[4]);           \
      acc[5] = fmaf(XA.w, wb.y, acc[5]);           \
      acc[6] = fmaf(XA.w, wb.z, acc[6]);           \
      acc[7] = fmaf(XA.w, wb.w, acc[7]); }

#define WK_STEP(KQ, CUR, NXT)                                          \
    { float4 xa = *(const float4*)&xsb[lane][(KQ) * 4];                \
      WK_ANCHOR(xa, CUR);                                              \
      __builtin_amdgcn_sched_barrier(0);                               \
      if ((KQ) < 7) {                                                  \
          _Pragma("unroll")                                            \
          for (int j = 0; j < 8; ++j) NXT[j] = wq4c[((KQ) + 1) * 8 + j]; \
      }                                                                \
      WK_REST(xa, CUR); }

    for (int c = 0; c < 32; ++c) {
        if (c < 31) {
            pf0 = *(const float4*)(gsrc + (size_t)(c + 1) * 32);
            pf1 = *(const float4*)(gsrc + (size_t)(c + 1) * 32 + 4);
        }
        const float4* wq4c = (const float4*)(wbase + c * 256);   // 64 f4, wave-uniform
        const float (*xsb)[36] = xs[c & 1];

        float4 wA[8], wB[8];
        #pragma unroll
        for (int j = 0; j < 8; ++j) wA[j] = wq4c[j];
        WK_STEP(0, wA, wB);
        WK_STEP(1, wB, wA);
        WK_STEP(2, wA, wB);
        WK_STEP(3, wB, wA);
        WK_STEP(4, wA, wB);
        WK_STEP(5, wB, wA);
        WK_STEP(6, wA, wB);
        WK_STEP(7, wB, wA);

        if (c < 31) {
            *(float4*)&xs[(c + 1) & 1][srow][sc * 8]     = pf0;
            *(float4*)&xs[(c + 1) & 1][srow][sc * 8 + 4] = pf1;
        }
        __syncthreads();
    }
#undef WK_STEP
#undef WK_REST
#undef WK_ANCHOR

    // epilogue: +bias (np: matmul then +bias), store 8 cols
    const float* bb = bqk + role * 64 + octg * 8;
    float* dst = (role ? kg : qg) + (size_t)(row0 + lane) * 64 + octg * 8;
    float4 o0 = make_float4(acc[0] + bb[0], acc[1] + bb[1],
                            acc[2] + bb[2], acc[3] + bb[3]);
    float4 o1 = make_float4(acc[4] + bb[4], acc[5] + bb[5],
                            acc[6] + bb[6], acc[7] + bb[7]);
    *(float4*)dst       = o0;
    *(float4*)(dst + 4) = o1;
}

// ---------------- K1b: features (p-chains + sincos), bit-identical d-chain.
// kP additionally stored transposed: kPgT[chain=b*16+m][t] (contiguous per chain).
__global__ __launch_bounds__(256) void k1b_feat(
    const float* __restrict__ qg, const float* __restrict__ kg,
    const float* __restrict__ w,
    float* __restrict__ qPg, float* __restrict__ kPg,
    float* __restrict__ kPgT)
{
    __shared__ float vals[16][132];   // q(0:64) | k(64:128)
    __shared__ float wT[8][68];       // w transposed [pcol][d]
    const int t    = threadIdx.x;
    const int row0 = blockIdx.x * 16;

    for (int i = t; i < 512; i += 256)
        wT[i >> 6][i & 63] = w[(i & 63) * 8 + (i >> 6)];
    {
        const int r = t >> 4, c4 = t & 15;
        *(float4*)&vals[r][c4 * 4]      = *(const float4*)&qg[(size_t)(row0 + r) * 64 + c4 * 4];
        *(float4*)&vals[r][64 + c4 * 4] = *(const float4*)&kg[(size_t)(row0 + r) * 64 + c4 * 4];
    }
    __syncthreads();

    const int frow = t >> 4;
    const int sub  = t & 15;
    const int pcol = sub & 7;
    const int isk  = sub >> 3;
    float p = 0.f;
    for (int d = 0; d < 64; ++d)
        p = fmaf(vals[frow][isk * 64 + d], wT[pcol][d], p);   // sequential d-chain
    double sd, cd;
    sincos((double)p, &sd, &cd);
    const float cf = (float)cd / SQ8F;
    const float sf = (float)sd / SQ8F;
    const int grow = row0 + frow;
    if (isk == 0) {
        qPg[(size_t)grow * 16 + pcol]     = cf;
        qPg[(size_t)grow * 16 + 8 + pcol] = sf;
    } else {
        kPg[(size_t)grow * 16 + pcol]     = cf;
        kPg[(size_t)grow * 16 + 8 + pcol] = sf;
        const int b  = grow >> 12;
        const int tt = grow & 4095;
        kPgT[(size_t)(b * 16 + pcol)     * 4096 + tt] = cf;
        kPgT[(size_t)(b * 16 + 8 + pcol) * 4096 + tt] = sf;
    }
}

// ---------------- K2s: gids 0..63 = one exact kSum chain per block (stage 16 KB
// to LDS, lane 0 runs the bit-exact ascending-t chain).
// gids 64.. = A-partials (A = kP^T x) with LDS kP tile + 8-deep x prefetch.
template<int RPS>
__global__ __launch_bounds__(256) void k2s(
    const float* __restrict__ x, const float* __restrict__ kPg,
    const float* __restrict__ kPgT,
    float* __restrict__ Apart, float* __restrict__ kSumF)
{
    __shared__ union KU {
        float4 kpL[RPS * 4];      // A-blocks: RPS rows x 16 m (<= 4 KB at RPS=64)
        float4 ch4[1024];         // chain blocks: one chain, 16 KB
    } smu;
    const int TS  = 4096 / RPS;
    const int gid = blockIdx.x;
    const int tid = threadIdx.x;

    if (gid < 64) {
        // kSum chain for (b,m) = gid: flat SEQUENTIAL f32 chain over t — numpy order.
        const float4* src = (const float4*)(kPgT + (size_t)gid * 4096);
        #pragma unroll 4
        for (int i = tid; i < 1024; i += 256)
            smu.ch4[i] = src[i];
        __syncthreads();
        if (tid == 0) {
            const float* cb = (const float*)smu.ch4;
            float s = 0.f;
            for (int i = 0; i < 4096; ++i) s += cb[i];   // ascending t, exact order
            kSumF[gid] = s;
        }
    } else {
        const int g   = gid - 64;
        const int csl = g & 3;
        const int ts  = (g >> 2) % TS;
        const int b   = g / (4 * TS);
        const size_t rowbase = (size_t)b * 4096 + (size_t)ts * RPS;

        for (int i = tid; i < RPS * 4; i += 256)
            smu.kpL[i] = ((const float4*)(kPg + rowbase * 16))[i];
        __syncthreads();

        float a[16];
        #pragma unroll
        for (int m = 0; m < 16; ++m) a[m] = 0.f;

        const float* xp = x + rowbase * 1024 + csl * 256 + tid;

        float xb[8];
        #pragma unroll
        for (int j = 0; j < 8; ++j) xb[j] = xp[(size_t)j * 1024];

        for (int r0 = 0; r0 < RPS; r0 += 8) {
            float xc[8];
            #pragma unroll
            for (int j = 0; j < 8; ++j) xc[j] = xb[j];
            if (r0 + 8 < RPS) {
                #pragma unroll
                for (int j = 0; j < 8; ++j)
                    xb[j] = xp[(size_t)(r0 + 8 + j) * 1024];
            }
            #pragma unroll
            for (int j = 0; j < 8; ++j) {
                const int r = r0 + j;
                const float xv = xc[j];
                float4 p0 = smu.kpL[r*4+0], p1 = smu.kpL[r*4+1],
                       p2 = smu.kpL[r*4+2], p3 = smu.kpL[r*4+3];
                a[0]  = fmaf(xv, p0.x, a[0]);  a[1]  = fmaf(xv, p0.y, a[1]);
                a[2]  = fmaf(xv, p0.z, a[2]);  a[3]  = fmaf(xv, p0.w, a[3]);
                a[4]  = fmaf(xv, p1.x, a[4]);  a[5]  = fmaf(xv, p1.y, a[5]);
                a[6]  = fmaf(xv, p1.z, a[6]);  a[7]  = fmaf(xv, p1.w, a[7]);
                a[8]  = fmaf(xv, p2.x, a[8]);  a[9]  = fmaf(xv, p2.y, a[9]);
                a[10] = fmaf(xv, p2.z, a[10]); a[11] = fmaf(xv, p2.w, a[11]);
                a[12] = fmaf(xv, p3.x, a[12]); a[13] = fmaf(xv, p3.y, a[13]);
                a[14] = fmaf(xv, p3.z, a[14]); a[15] = fmaf(xv, p3.w, a[15]);
            }
        }
        float* ap = Apart + (size_t)(b * TS + ts) * 16 * 1024 + csl * 256 + tid;
        #pragma unroll
        for (int m = 0; m < 16; ++m) ap[(size_t)m * 1024] = a[m];
    }
}

// ---------------- K2t: per (b, cseg of 16 c): reduce Ts tiles -> Ared, then Ared@Wv
__global__ __launch_bounds__(256) void k2t(
    const float* __restrict__ Apart, const float* __restrict__ Wv,
    float* __restrict__ Spart2, int TS)
{
    __shared__ float AredL[16][16];
    __shared__ float WvL[16 * 64];
    const int gid  = blockIdx.x;        // 256 = 4b x 64cseg
    const int b    = gid >> 6;
    const int cseg = gid & 63;
    const int tid  = threadIdx.x;

    {
        const int m  = tid >> 4;
        const int cc = tid & 15;
        const float* src = Apart + (size_t)(b * TS) * 16 * 1024
                         + (size_t)m * 1024 + cseg * 16 + cc;
        float s = 0.f;
        for (int ts = 0; ts < TS; ++ts) s += src[(size_t)ts * 16 * 1024];
        AredL[m][cc] = s;
    }
    ((float4*)WvL)[tid] = ((const float4*)(Wv + (size_t)(cseg * 16) * 64))[tid];
    __syncthreads();

    {
        const int m  = tid >> 4;
        const int d4 = tid & 15;
        float4 acc = make_float4(0.f, 0.f, 0.f, 0.f);
        #pragma unroll
        for (int cc = 0; cc < 16; ++cc) {
            float av = AredL[m][cc];
            float4 wv4 = ((const float4*)WvL)[cc * 16 + d4];
            acc.x = fmaf(av, wv4.x, acc.x);
            acc.y = fmaf(av, wv4.y, acc.y);
            acc.z = fmaf(av, wv4.z, acc.z);
            acc.w = fmaf(av, wv4.w, acc.w);
        }
        ((float4*)(Spart2 + (size_t)(b * 64 + cseg) * 1024))[tid] = acc;
    }
}

// ---------------- K3: assemble S (+kSum*bv), D = sequential mul+add, N, out = N/D
__global__ __launch_bounds__(256) void k3_out(
    const float* __restrict__ qPg, const float* __restrict__ Spart2,
    const float* __restrict__ kSumF, const float* __restrict__ bv,
    float* __restrict__ out)
{
    __shared__ float S_lds[1024];
    __shared__ float ks[16];
    const int t = threadIdx.x;
    const int b = blockIdx.x >> 6;

    if (t < 16) ks[t] = kSumF[b * 16 + t];
    {
        const int m  = t >> 4;
        const int d4 = t & 15;
        float4 s = make_float4(0.f, 0.f, 0.f, 0.f);
        for (int cseg = 0; cseg < 64; ++cseg) {
            float4 v = ((const float4*)(Spart2 + (size_t)(b * 64 + cseg) * 1024))[t];
            s.x += v.x; s.y += v.y; s.z += v.z; s.w += v.w;
        }
        const float kv = kSumF[b * 16 + m];
        const float4 bvv = ((const float4*)bv)[d4];
        s.x = fmaf(kv, bvv.x, s.x);
        s.y = fmaf(kv, bvv.y, s.y);
        s.z = fmaf(kv, bvv.z, s.z);
        s.w = fmaf(kv, bvv.w, s.w);
        ((float4*)S_lds)[t] = s;
    }
    __syncthreads();

    const int row = blockIdx.x * BM + (t >> 2);
    const int c0  = (t & 3) * 16;
    const float4* qp = (const float4*)(qPg + (size_t)row * 16);
    float4 q0 = qp[0], q1 = qp[1], q2 = qp[2], q3 = qp[3];
    float q[16] = { q0.x,q0.y,q0.z,q0.w, q1.x,q1.y,q1.z,q1.w,
                    q2.x,q2.y,q2.z,q2.w, q3.x,q3.y,q3.z,q3.w };

    float D = 0.f;
    #pragma unroll
    for (int m = 0; m < 16; ++m)
        D = __fadd_rn(D, __fmul_rn(q[m], ks[m]));   // no FMA: mirror einsum

    float a[16];
    #pragma unroll
    for (int j = 0; j < 16; ++j) a[j] = 0.f;
    #pragma unroll
    for (int m = 0; m < 16; ++m) {
        const float qm = q[m];
        const float* sr = S_lds + m * 64 + c0;
        #pragma unroll
        for (int j = 0; j < 16; ++j) a[j] = fmaf(qm, sr[j], a[j]);
    }

    float r[16];
    #pragma unroll
    for (int j = 0; j < 16; ++j) r[j] = a[j] / D;

    float4* op = (float4*)(out + (size_t)row * 64 + c0);
    op[0] = make_float4(r[0],  r[1],  r[2],  r[3]);
    op[1] = make_float4(r[4],  r[5],  r[6],  r[7]);
    op[2] = make_float4(r[8],  r[9],  r[10], r[11]);
    op[3] = make_float4(r[12], r[13], r[14], r[15]);
}

extern "C" void kernel_launch(void* const* d_in, const int* in_sizes, int n_in,
                              void* d_out, int out_size, void* d_ws, size_t ws_size,
                              hipStream_t stream)
{
    const float* x  = (const float*)d_in[0];
    const float* Wq = (const float*)d_in[1];
    const float* bq = (const float*)d_in[2];
    const float* Wk = (const float*)d_in[3];
    const float* bk = (const float*)d_in[4];
    const float* Wv = (const float*)d_in[5];
    const float* bv = (const float*)d_in[6];
    const float* w  = (const float*)d_in[7];

    char* ws = (char*)d_ws;
    float* Wp     = (float*)(ws + WP_OFF);
    float* bqk    = (float*)(ws + BQK_OFF);
    float* qPg    = (float*)(ws + QP_OFF);
    float* kPg    = (float*)(ws + KP_OFF);
    float* kPgT   = (float*)(ws + KPT_OFF);
    float* Spart2 = (float*)(ws + SP2_OFF);
    float* kSumF  = (float*)(ws + KS_OFF);
    float* qg     = (float*)(ws + QG_OFF);
    float* kg     = (float*)(ws + KG_OFF);
    float* Apart  = (float*)(ws + AP_OFF);
    float* out    = (float*)d_out;

    k0_pack<<<dim3(129), dim3(256), 0, stream>>>(Wq, bq, Wk, bk, Wp, bqk);
    k1_main<<<dim3(1024), dim3(256), 0, stream>>>(x, Wp, bqk, qg, kg);
    k1b_feat<<<dim3(1024), dim3(256), 0, stream>>>(qg, kg, w, qPg, kPg, kPgT);

    // Apart tiering by available scratch: Ts tiles of RPS rows (Ts*262144 B each)
    if (ws_size >= (size_t)AP_OFF + 4ull * 64 * 16 * 1024 * 4) {
        k2s<64><<<dim3(1088), dim3(256), 0, stream>>>(x, kPg, kPgT, Apart, kSumF);
        k2t<<<dim3(256), dim3(256), 0, stream>>>(Apart, Wv, Spart2, 64);
    } else if (ws_size >= (size_t)AP_OFF + 4ull * 32 * 16 * 1024 * 4) {
        k2s<128><<<dim3(576), dim3(256), 0, stream>>>(x, kPg, kPgT, Apart, kSumF);
        k2t<<<dim3(256), dim3(256), 0, stream>>>(Apart, Wv, Spart2, 32);
    } else {
        k2s<256><<<dim3(320), dim3(256), 0, stream>>>(x, kPg, kPgT, Apart, kSumF);
        k2t<<<dim3(256), dim3(256), 0, stream>>>(Apart, Wv, Spart2, 16);
    }

    k3_out<<<dim3(256), dim3(256), 0, stream>>>(qPg, Spart2, kSumF, bv, out);
}

// Round 20
// 128.482 us; speedup vs baseline: 1.0867x; 1.0867x over previous
//
#include <hip/hip_runtime.h>
#include <math.h>

// ---- problem constants ----
#define NE   1024
#define ROWS 16384
#define BM   64
#define SQ8F 2.8284271247461903f   // float32(math.sqrt(8)) as numpy casts it

// ---- workspace layout (bytes); Apart LAST so its size can flex with ws_size ----
#define WP_OFF   0u          // Wp: [2r][8oct][1024k][8c] f32 = 524288
#define BQK_OFF  524288u     // bqk: 128 f32 = 512
#define QP_OFF   524800u     // qPg: 16384*16 f32 = 1048576
#define KP_OFF   1573376u    // kPg: 16384*16 f32 = 1048576   [t][16]
#define KPT_OFF  2621952u    // kPgT: [64 chain][4096 t] f32 = 1048576
#define SP2_OFF  3670528u    // Spart2: 4*64*16*64 f32 = 1048576
#define KS_OFF   4719104u    // kSumF: 64 f32 = 256
#define QG_OFF   4719360u    // qg: 16384*64 f32 = 4194304
#define KG_OFF   8913664u    // kg: 16384*64 f32 = 4194304
#define AP_OFF   13107968u   // Apart: 4*Ts tiles * 16*1024 f32 (Ts=64 -> 16 MB)

// ---------------- K0: pack Wp k-major per 8-col octet (pure copy), bqk = [bq | bk]
__global__ __launch_bounds__(256) void k0_pack(
    const float* __restrict__ Wq, const float* __restrict__ bq,
    const float* __restrict__ Wk, const float* __restrict__ bk,
    float* __restrict__ Wp, float* __restrict__ bqk)
{
    int idx = blockIdx.x * 256 + threadIdx.x;
    if (idx < 32768) {                       // 2 roles * 1024 k * 16 float4
        int role = idx >> 14;
        int rem  = idx & 16383;
        int k = rem >> 4, c4 = rem & 15;
        float4 v = ((const float4*)(role ? Wk : Wq))[k * 16 + c4];
        int oct = c4 >> 1, pos = c4 & 1;
        ((float4*)Wp)[(size_t)(role * 8 + oct) * 2048 + k * 2 + pos] = v;
    } else if (idx < 32768 + 128) {
        int j = idx - 32768;
        bqk[j] = (j < 64) ? bq[j] : bk[j - 64];
    }
}

// ---------------- K1: 1024 blocks x 256 thr: GEMM only, C=8 cols/thread.
// (round-14 structure, verified 68-69 us: 64 rows x 32 cols, variant = bid>>8)
// k1 plateau: 6 restructuring attempts (r8,r9,r11,r15,r16,r19) all regressed;
// the W s_load lgkmcnt(0) drain + fixed 4 waves/SIMD (C=8/DS tradeoff) bind it.
__global__ __launch_bounds__(256, 4) void k1_main(
    const float* __restrict__ x, const float* __restrict__ Wp,
    const float* __restrict__ bqk,
    float* __restrict__ qg, float* __restrict__ kg)
{
    __shared__ float xs[2][64][36];   // x chunk (K=32), double-buffered, 18 KB

    const int t    = threadIdx.x;
    const int lane = t & 63;
    const int wv   = __builtin_amdgcn_readfirstlane(t >> 6);   // 0..3
    const int bid  = blockIdx.x;
    const int variant = bid >> 8;     // 0..3: 32-col slice
    const int rb      = bid & 255;
    const int role = variant >> 1;
    const int octg = (variant & 1) * 4 + wv;   // 0..7 octet within role
    const int row0 = rb * 64;

    float acc[8];
    #pragma unroll
    for (int j = 0; j < 8; ++j) acc[j] = 0.f;

    const int srow = t >> 2;          // 0..63
    const int sc   = t & 3;           // 0..3 (8 floats each)
    const float* gsrc = x + (size_t)(row0 + srow) * NE + sc * 8;

    const float* wbase = Wp + (size_t)(role * 8 + octg) * 8192;  // wave-uniform

    float4 pf0 = *(const float4*)gsrc;
    float4 pf1 = *(const float4*)(gsrc + 4);
    *(float4*)&xs[0][srow][sc * 8]     = pf0;
    *(float4*)&xs[0][srow][sc * 8 + 4] = pf1;
    __syncthreads();

    for (int c = 0; c < 32; ++c) {
        if (c < 31) {
            pf0 = *(const float4*)(gsrc + (size_t)(c + 1) * 32);
            pf1 = *(const float4*)(gsrc + (size_t)(c + 1) * 32 + 4);
        }
        const float* wc = wbase + c * 256;     // 32 k x 8 cols, contiguous
        const float (*xsb)[36] = xs[c & 1];
        #pragma unroll
        for (int kq = 0; kq < 8; ++kq) {
            float4 xa = *(const float4*)&xsb[lane][kq * 4];
            const float4* wq4 = (const float4*)(wc + kq * 32);
            {
                float4 wa = wq4[0], wb = wq4[1];
                acc[0] = fmaf(xa.x, wa.x, acc[0]);
                acc[1] = fmaf(xa.x, wa.y, acc[1]);
                acc[2] = fmaf(xa.x, wa.z, acc[2]);
                acc[3] = fmaf(xa.x, wa.w, acc[3]);
                acc[4] = fmaf(xa.x, wb.x, acc[4]);
                acc[5] = fmaf(xa.x, wb.y, acc[5]);
                acc[6] = fmaf(xa.x, wb.z, acc[6]);
                acc[7] = fmaf(xa.x, wb.w, acc[7]);
            }
            {
                float4 wa = wq4[2], wb = wq4[3];
                acc[0] = fmaf(xa.y, wa.x, acc[0]);
                acc[1] = fmaf(xa.y, wa.y, acc[1]);
                acc[2] = fmaf(xa.y, wa.z, acc[2]);
                acc[3] = fmaf(xa.y, wa.w, acc[3]);
                acc[4] = fmaf(xa.y, wb.x, acc[4]);
                acc[5] = fmaf(xa.y, wb.y, acc[5]);
                acc[6] = fmaf(xa.y, wb.z, acc[6]);
                acc[7] = fmaf(xa.y, wb.w, acc[7]);
            }
            {
                float4 wa = wq4[4], wb = wq4[5];
                acc[0] = fmaf(xa.z, wa.x, acc[0]);
                acc[1] = fmaf(xa.z, wa.y, acc[1]);
                acc[2] = fmaf(xa.z, wa.z, acc[2]);
                acc[3] = fmaf(xa.z, wa.w, acc[3]);
                acc[4] = fmaf(xa.z, wb.x, acc[4]);
                acc[5] = fmaf(xa.z, wb.y, acc[5]);
                acc[6] = fmaf(xa.z, wb.z, acc[6]);
                acc[7] = fmaf(xa.z, wb.w, acc[7]);
            }
            {
                float4 wa = wq4[6], wb = wq4[7];
                acc[0] = fmaf(xa.w, wa.x, acc[0]);
                acc[1] = fmaf(xa.w, wa.y, acc[1]);
                acc[2] = fmaf(xa.w, wa.z, acc[2]);
                acc[3] = fmaf(xa.w, wa.w, acc[3]);
                acc[4] = fmaf(xa.w, wb.x, acc[4]);
                acc[5] = fmaf(xa.w, wb.y, acc[5]);
                acc[6] = fmaf(xa.w, wb.z, acc[6]);
                acc[7] = fmaf(xa.w, wb.w, acc[7]);
            }
        }
        if (c < 31) {
            *(float4*)&xs[(c + 1) & 1][srow][sc * 8]     = pf0;
            *(float4*)&xs[(c + 1) & 1][srow][sc * 8 + 4] = pf1;
        }
        __syncthreads();
    }

    // epilogue: +bias (np: matmul then +bias), store 8 cols
    const float* bb = bqk + role * 64 + octg * 8;
    float* dst = (role ? kg : qg) + (size_t)(row0 + lane) * 64 + octg * 8;
    float4 o0 = make_float4(acc[0] + bb[0], acc[1] + bb[1],
                            acc[2] + bb[2], acc[3] + bb[3]);
    float4 o1 = make_float4(acc[4] + bb[4], acc[5] + bb[5],
                            acc[6] + bb[6], acc[7] + bb[7]);
    *(float4*)dst       = o0;
    *(float4*)(dst + 4) = o1;
}

// ---------------- K1b: features (p-chains + sincos), bit-identical d-chain.
// kP additionally stored transposed: kPgT[chain=b*16+m][t] (contiguous per chain).
__global__ __launch_bounds__(256) void k1b_feat(
    const float* __restrict__ qg, const float* __restrict__ kg,
    const float* __restrict__ w,
    float* __restrict__ qPg, float* __restrict__ kPg,
    float* __restrict__ kPgT)
{
    __shared__ float vals[16][132];   // q(0:64) | k(64:128)
    __shared__ float wT[8][68];       // w transposed [pcol][d]
    const int t    = threadIdx.x;
    const int row0 = blockIdx.x * 16;

    for (int i = t; i < 512; i += 256)
        wT[i >> 6][i & 63] = w[(i & 63) * 8 + (i >> 6)];
    {
        const int r = t >> 4, c4 = t & 15;
        *(float4*)&vals[r][c4 * 4]      = *(const float4*)&qg[(size_t)(row0 + r) * 64 + c4 * 4];
        *(float4*)&vals[r][64 + c4 * 4] = *(const float4*)&kg[(size_t)(row0 + r) * 64 + c4 * 4];
    }
    __syncthreads();

    const int frow = t >> 4;
    const int sub  = t & 15;
    const int pcol = sub & 7;
    const int isk  = sub >> 3;
    float p = 0.f;
    for (int d = 0; d < 64; ++d)
        p = fmaf(vals[frow][isk * 64 + d], wT[pcol][d], p);   // sequential d-chain
    double sd, cd;
    sincos((double)p, &sd, &cd);
    const float cf = (float)cd / SQ8F;
    const float sf = (float)sd / SQ8F;
    const int grow = row0 + frow;
    if (isk == 0) {
        qPg[(size_t)grow * 16 + pcol]     = cf;
        qPg[(size_t)grow * 16 + 8 + pcol] = sf;
    } else {
        kPg[(size_t)grow * 16 + pcol]     = cf;
        kPg[(size_t)grow * 16 + 8 + pcol] = sf;
        const int b  = grow >> 12;
        const int tt = grow & 4095;
        kPgT[(size_t)(b * 16 + pcol)     * 4096 + tt] = cf;
        kPgT[(size_t)(b * 16 + 8 + pcol) * 4096 + tt] = sf;
    }
}

// ---------------- K2s: gids 0..63 = one exact kSum chain per block (stage 16 KB
// to LDS, lane 0 runs the bit-exact ascending-t chain).
// gids 64.. = A-partials (A = kP^T x) with LDS kP tile + 8-deep x prefetch.
template<int RPS>
__global__ __launch_bounds__(256) void k2s(
    const float* __restrict__ x, const float* __restrict__ kPg,
    const float* __restrict__ kPgT,
    float* __restrict__ Apart, float* __restrict__ kSumF)
{
    __shared__ union KU {
        float4 kpL[RPS * 4];      // A-blocks: RPS rows x 16 m (<= 4 KB at RPS=64)
        float4 ch4[1024];         // chain blocks: one chain, 16 KB
    } smu;
    const int TS  = 4096 / RPS;
    const int gid = blockIdx.x;
    const int tid = threadIdx.x;

    if (gid < 64) {
        // kSum chain for (b,m) = gid: flat SEQUENTIAL f32 chain over t — numpy order.
        const float4* src = (const float4*)(kPgT + (size_t)gid * 4096);
        #pragma unroll 4
        for (int i = tid; i < 1024; i += 256)
            smu.ch4[i] = src[i];
        __syncthreads();
        if (tid == 0) {
            const float* cb = (const float*)smu.ch4;
            float s = 0.f;
            for (int i = 0; i < 4096; ++i) s += cb[i];   // ascending t, exact order
            kSumF[gid] = s;
        }
    } else {
        const int g   = gid - 64;
        const int csl = g & 3;
        const int ts  = (g >> 2) % TS;
        const int b   = g / (4 * TS);
        const size_t rowbase = (size_t)b * 4096 + (size_t)ts * RPS;

        for (int i = tid; i < RPS * 4; i += 256)
            smu.kpL[i] = ((const float4*)(kPg + rowbase * 16))[i];
        __syncthreads();

        float a[16];
        #pragma unroll
        for (int m = 0; m < 16; ++m) a[m] = 0.f;

        const float* xp = x + rowbase * 1024 + csl * 256 + tid;

        float xb[8];
        #pragma unroll
        for (int j = 0; j < 8; ++j) xb[j] = xp[(size_t)j * 1024];

        for (int r0 = 0; r0 < RPS; r0 += 8) {
            float xc[8];
            #pragma unroll
            for (int j = 0; j < 8; ++j) xc[j] = xb[j];
            if (r0 + 8 < RPS) {
                #pragma unroll
                for (int j = 0; j < 8; ++j)
                    xb[j] = xp[(size_t)(r0 + 8 + j) * 1024];
            }
            #pragma unroll
            for (int j = 0; j < 8; ++j) {
                const int r = r0 + j;
                const float xv = xc[j];
                float4 p0 = smu.kpL[r*4+0], p1 = smu.kpL[r*4+1],
                       p2 = smu.kpL[r*4+2], p3 = smu.kpL[r*4+3];
                a[0]  = fmaf(xv, p0.x, a[0]);  a[1]  = fmaf(xv, p0.y, a[1]);
                a[2]  = fmaf(xv, p0.z, a[2]);  a[3]  = fmaf(xv, p0.w, a[3]);
                a[4]  = fmaf(xv, p1.x, a[4]);  a[5]  = fmaf(xv, p1.y, a[5]);
                a[6]  = fmaf(xv, p1.z, a[6]);  a[7]  = fmaf(xv, p1.w, a[7]);
                a[8]  = fmaf(xv, p2.x, a[8]);  a[9]  = fmaf(xv, p2.y, a[9]);
                a[10] = fmaf(xv, p2.z, a[10]); a[11] = fmaf(xv, p2.w, a[11]);
                a[12] = fmaf(xv, p3.x, a[12]); a[13] = fmaf(xv, p3.y, a[13]);
                a[14] = fmaf(xv, p3.z, a[14]); a[15] = fmaf(xv, p3.w, a[15]);
            }
        }
        float* ap = Apart + (size_t)(b * TS + ts) * 16 * 1024 + csl * 256 + tid;
        #pragma unroll
        for (int m = 0; m < 16; ++m) ap[(size_t)m * 1024] = a[m];
    }
}

// ---------------- K2t: per (b, cseg of 16 c): reduce Ts tiles -> Ared, then Ared@Wv
__global__ __launch_bounds__(256) void k2t(
    const float* __restrict__ Apart, const float* __restrict__ Wv,
    float* __restrict__ Spart2, int TS)
{
    __shared__ float AredL[16][16];
    __shared__ float WvL[16 * 64];
    const int gid  = blockIdx.x;        // 256 = 4b x 64cseg
    const int b    = gid >> 6;
    const int cseg = gid & 63;
    const int tid  = threadIdx.x;

    {
        const int m  = tid >> 4;
        const int cc = tid & 15;
        const float* src = Apart + (size_t)(b * TS) * 16 * 1024
                         + (size_t)m * 1024 + cseg * 16 + cc;
        float s = 0.f;
        for (int ts = 0; ts < TS; ++ts) s += src[(size_t)ts * 16 * 1024];
        AredL[m][cc] = s;
    }
    ((float4*)WvL)[tid] = ((const float4*)(Wv + (size_t)(cseg * 16) * 64))[tid];
    __syncthreads();

    {
        const int m  = tid >> 4;
        const int d4 = tid & 15;
        float4 acc = make_float4(0.f, 0.f, 0.f, 0.f);
        #pragma unroll
        for (int cc = 0; cc < 16; ++cc) {
            float av = AredL[m][cc];
            float4 wv4 = ((const float4*)WvL)[cc * 16 + d4];
            acc.x = fmaf(av, wv4.x, acc.x);
            acc.y = fmaf(av, wv4.y, acc.y);
            acc.z = fmaf(av, wv4.z, acc.z);
            acc.w = fmaf(av, wv4.w, acc.w);
        }
        ((float4*)(Spart2 + (size_t)(b * 64 + cseg) * 1024))[tid] = acc;
    }
}

// ---------------- K3: assemble S (+kSum*bv), D = sequential mul+add, N, out = N/D
__global__ __launch_bounds__(256) void k3_out(
    const float* __restrict__ qPg, const float* __restrict__ Spart2,
    const float* __restrict__ kSumF, const float* __restrict__ bv,
    float* __restrict__ out)
{
    __shared__ float S_lds[1024];
    __shared__ float ks[16];
    const int t = threadIdx.x;
    const int b = blockIdx.x >> 6;

    if (t < 16) ks[t] = kSumF[b * 16 + t];
    {
        const int m  = t >> 4;
        const int d4 = t & 15;
        float4 s = make_float4(0.f, 0.f, 0.f, 0.f);
        for (int cseg = 0; cseg < 64; ++cseg) {
            float4 v = ((const float4*)(Spart2 + (size_t)(b * 64 + cseg) * 1024))[t];
            s.x += v.x; s.y += v.y; s.z += v.z; s.w += v.w;
        }
        const float kv = kSumF[b * 16 + m];
        const float4 bvv = ((const float4*)bv)[d4];
        s.x = fmaf(kv, bvv.x, s.x);
        s.y = fmaf(kv, bvv.y, s.y);
        s.z = fmaf(kv, bvv.z, s.z);
        s.w = fmaf(kv, bvv.w, s.w);
        ((float4*)S_lds)[t] = s;
    }
    __syncthreads();

    const int row = blockIdx.x * BM + (t >> 2);
    const int c0  = (t & 3) * 16;
    const float4* qp = (const float4*)(qPg + (size_t)row * 16);
    float4 q0 = qp[0], q1 = qp[1], q2 = qp[2], q3 = qp[3];
    float q[16] = { q0.x,q0.y,q0.z,q0.w, q1.x,q1.y,q1.z,q1.w,
                    q2.x,q2.y,q2.z,q2.w, q3.x,q3.y,q3.z,q3.w };

    float D = 0.f;
    #pragma unroll
    for (int m = 0; m < 16; ++m)
        D = __fadd_rn(D, __fmul_rn(q[m], ks[m]));   // no FMA: mirror einsum

    float a[16];
    #pragma unroll
    for (int j = 0; j < 16; ++j) a[j] = 0.f;
    #pragma unroll
    for (int m = 0; m < 16; ++m) {
        const float qm = q[m];
        const float* sr = S_lds + m * 64 + c0;
        #pragma unroll
        for (int j = 0; j < 16; ++j) a[j] = fmaf(qm, sr[j], a[j]);
    }

    float r[16];
    #pragma unroll
    for (int j = 0; j < 16; ++j) r[j] = a[j] / D;

    float4* op = (float4*)(out + (size_t)row * 64 + c0);
    op[0] = make_float4(r[0],  r[1],  r[2],  r[3]);
    op[1] = make_float4(r[4],  r[5],  r[6],  r[7]);
    op[2] = make_float4(r[8],  r[9],  r[10], r[11]);
    op[3] = make_float4(r[12], r[13], r[14], r[15]);
}

extern "C" void kernel_launch(void* const* d_in, const int* in_sizes, int n_in,
                              void* d_out, int out_size, void* d_ws, size_t ws_size,
                              hipStream_t stream)
{
    const float* x  = (const float*)d_in[0];
    const float* Wq = (const float*)d_in[1];
    const float* bq = (const float*)d_in[2];
    const float* Wk = (const float*)d_in[3];
    const float* bk = (const float*)d_in[4];
    const float* Wv = (const float*)d_in[5];
    const float* bv = (const float*)d_in[6];
    const float* w  = (const float*)d_in[7];

    char* ws = (char*)d_ws;
    float* Wp     = (float*)(ws + WP_OFF);
    float* bqk    = (float*)(ws + BQK_OFF);
    float* qPg    = (float*)(ws + QP_OFF);
    float* kPg    = (float*)(ws + KP_OFF);
    float* kPgT   = (float*)(ws + KPT_OFF);
    float* Spart2 = (float*)(ws + SP2_OFF);
    float* kSumF  = (float*)(ws + KS_OFF);
    float* qg     = (float*)(ws + QG_OFF);
    float* kg     = (float*)(ws + KG_OFF);
    float* Apart  = (float*)(ws + AP_OFF);
    float* out    = (float*)d_out;

    k0_pack<<<dim3(129), dim3(256), 0, stream>>>(Wq, bq, Wk, bk, Wp, bqk);
    k1_main<<<dim3(1024), dim3(256), 0, stream>>>(x, Wp, bqk, qg, kg);
    k1b_feat<<<dim3(1024), dim3(256), 0, stream>>>(qg, kg, w, qPg, kPg, kPgT);

    // Apart tiering by available scratch: Ts tiles of RPS rows (Ts*262144 B each)
    if (ws_size >= (size_t)AP_OFF + 4ull * 64 * 16 * 1024 * 4) {
        k2s<64><<<dim3(1088), dim3(256), 0, stream>>>(x, kPg, kPgT, Apart, kSumF);
        k2t<<<dim3(256), dim3(256), 0, stream>>>(Apart, Wv, Spart2, 64);
    } else if (ws_size >= (size_t)AP_OFF + 4ull * 32 * 16 * 1024 * 4) {
        k2s<128><<<dim3(576), dim3(256), 0, stream>>>(x, kPg, kPgT, Apart, kSumF);
        k2t<<<dim3(256), dim3(256), 0, stream>>>(Apart, Wv, Spart2, 32);
    } else {
        k2s<256><<<dim3(320), dim3(256), 0, stream>>>(x, kPg, kPgT, Apart, kSumF);
        k2t<<<dim3(256), dim3(256), 0, stream>>>(Apart, Wv, Spart2, 16);
    }

    k3_out<<<dim3(256), dim3(256), 0, stream>>>(qPg, Spart2, kSumF, bv, out);
}